// Round 4
// baseline (1020.957 us; speedup 1.0000x reference)
//
#include <hip/hip_runtime.h>
#include <cstdint>
#include <cstddef>

// Problem constants (match reference: B=64, L=512, STEPS=20)
#define LDIM 512
#define BATCH 64
#define NSTEPS 20
#define NTHREADS 256
#define PTHREADS 1024
#define CNT_STRIDE 16  // 64 B per counter: no atomic line sharing across batches

using f4 = __attribute__((ext_vector_type(4))) float;
using h4 = __attribute__((ext_vector_type(4))) _Float16;

#define MU_MASKED (-1024.0f)   // exact in fp16; sentinel for M==0
#define MU_THRESH (-512.0f)

__device__ __forceinline__ float relu_f(float x) { return fmaxf(x, 0.0f); }
__device__ __forceinline__ float sign_f(float x) {
  return (x > 0.0f) ? 1.0f : ((x < 0.0f) ? -1.0f : 0.0f);
}
__device__ __forceinline__ float wave_reduce_sum(float v) {
  v += __shfl_xor(v, 32);
  v += __shfl_xor(v, 16);
  v += __shfl_xor(v, 8);
  v += __shfl_xor(v, 4);
  v += __shfl_xor(v, 2);
  v += __shfl_xor(v, 1);
  return v;
}
// Agent-scope RELAXED accesses: compile to sc1 (L1/L2-bypassing) ops serviced
// at the coherence point. Never acquire/threadfence here: agent-acquire emits
// buffer_inv (full per-XCD L2 invalidate) — round-1 spent 97% of time there.
__device__ __forceinline__ void st_agent(float* p, float v) {
  __hip_atomic_store(p, v, __ATOMIC_RELAXED, __HIP_MEMORY_SCOPE_AGENT);
}
__device__ __forceinline__ float ld_agent(const float* p) {
  return __hip_atomic_load(p, __ATOMIC_RELAXED, __HIP_MEMORY_SCOPE_AGENT);
}

// ---------------------------------------------------------------------------
// k_build: MU[b][i][j] = M_ij ? fp16(0.5*(sc_ij + sc_ji) - s) : -1024, via
// 64x64 tile pairs (coalesced transpose through LDS). Also zeroes the
// per-batch sync counters (flushed by the end-of-kernel release).
// Grid: BATCH * 36 tile pairs; 256 threads.
// ---------------------------------------------------------------------------
__global__ __launch_bounds__(NTHREADS) void k_build(
    const float* __restrict__ scores, const float* __restrict__ M,
    const float* __restrict__ s_ptr, _Float16* __restrict__ MU,
    unsigned int* __restrict__ counter) {
  __shared__ float Sa[64][65];
  __shared__ float Sb[64][65];
  if (blockIdx.x < BATCH && threadIdx.x == 0) counter[blockIdx.x * CNT_STRIDE] = 0u;
  const int b = blockIdx.x / 36;
  int rem = blockIdx.x % 36;
  int ti = 0;
  while (rem >= 8 - ti) {
    rem -= 8 - ti;
    ti++;
  }
  const int tj = ti + rem;
  const int tid = threadIdx.x;
  const int c = tid & 63;
  const int r0 = tid >> 6;
  const float sval = s_ptr[0];
  const size_t mb = (size_t)b * LDIM * LDIM;
#pragma unroll
  for (int k = 0; k < 16; k++) {
    const int r = 4 * k + r0;
    Sa[r][c] = scores[mb + (size_t)(ti * 64 + r) * LDIM + tj * 64 + c];
    Sb[r][c] = scores[mb + (size_t)(tj * 64 + r) * LDIM + ti * 64 + c];
  }
  __syncthreads();
#pragma unroll
  for (int k = 0; k < 16; k++) {
    const int r = 4 * k + r0;
    const size_t idx_ij = mb + (size_t)(ti * 64 + r) * LDIM + tj * 64 + c;
    const float mij = M[idx_ij];
    const float us = 0.5f * (Sa[r][c] + Sb[c][r]) - sval;
    MU[idx_ij] = (_Float16)((mij != 0.0f) ? us : MU_MASKED);
    if (ti != tj) {
      const size_t idx_ji = mb + (size_t)(tj * 64 + r) * LDIM + ti * 64 + c;
      const float mji = M[idx_ji];
      const float usj = 0.5f * (Sb[r][c] + Sa[c][r]) - sval;
      MU[idx_ji] = (_Float16)((mji != 0.0f) ? usj : MU_MASKED);
    }
  }
}

// ---------------------------------------------------------------------------
// k_persist: all 20 steps with A_hat in VGPRs and MU (fp16) in LDS — zero
// bulk global traffic inside the step loop (rho is a 1 MB L2-resident read).
// Grid 256 blocks x 1024 threads, 1 block/CU (forced by 146 KB LDS).
// Per wave (16 waves): 8 rows, f4 ahv[8][2] (64 VGPRs of state).
// OCCUPANCY/VGPR CONTRACT: amdgpu_waves_per_eu(4,4) pins the allocator to the
// 4-waves/SIMD budget (128 VGPRs). Round-3's __launch_bounds__(1024,4) only
// set a MINIMUM — the allocator squeezed to 64 VGPRs chasing 8 waves/EU that
// the LDS footprint forbids, spilling all of ahv (745 MB of scratch writes).
// The per-step row loop is split into two 4-row groups with sched_barrier(0)
// between them so hoisted MU/rho loads can't blow the 128-reg live range.
// Cross-block exchange per step: 2.5 KB of partials via sc1 relaxed atomics +
// a monotonic per-batch arrival counter. NO fences, NO acquire.
// ---------------------------------------------------------------------------
__global__ __launch_bounds__(PTHREADS)
__attribute__((amdgpu_waves_per_eu(4, 4))) void k_persist(
    const float* __restrict__ scores, const _Float16* __restrict__ MU,
    const float* __restrict__ rho_p, const float* __restrict__ w_ptr,
    const float* __restrict__ alpha_ptr, const float* __restrict__ belt_ptr,
    const float* __restrict__ lra_ptr, const float* __restrict__ lrb_ptr,
    float* __restrict__ rowpart, float* __restrict__ colpart,
    unsigned int* __restrict__ counter, float* __restrict__ Ah) {
  __shared__ _Float16 muL[128][LDIM];  // 128 KB: step-invariant masked usym
  __shared__ float stage[8][LDIM];     // 16 KB: cross-wave col-sum staging
  __shared__ float lmsgS[LDIM];        // 2 KB   (total 146 KB <= 160 KB)

  const int tid = threadIdx.x;
  const int lane = tid & 63;
  const int w = tid >> 6;
  const int b = blockIdx.x & (BATCH - 1);
  const int sb = blockIdx.x >> 6;
  const int wrow = sb * 128 + w * 8;
  const int j0 = lane << 2;
  const size_t mb = (size_t)b * LDIM * LDIM;

  const float wv = w_ptr[0];
  const float belt = belt_ptr[0];
  const float lra = lra_ptr[0];
  const float lrb = lrb_ptr[0];
  float at = alpha_ptr[0];  // a_t = alpha * lra^sp, updated iteratively
  float lrbp = 1.0f;        // lrb^(sp-1) for sp>=1
  float lm_reg = 0.0f;      // Lm[tid] (valid for tid < LDIM)

  const size_t RP = (size_t)BATCH * LDIM;      // rowpart parity stride
  const size_t CP = (size_t)BATCH * 4 * LDIM;  // colpart parity stride
  unsigned int* const cnt = counter + b * CNT_STRIDE;

  f4 ahv[8][2];
  float colacc[8];

  // __syncthreads() drains vmcnt per wave, so all waves' sc1 partial stores
  // are at the coherence point before tid0's counter add. Spin load is
  // RELAXED (sc1 loads always read fresh; no cache maintenance).
#define ARRIVE_WAIT(tgt)                                                       \
  do {                                                                         \
    __syncthreads();                                                           \
    if (tid == 0) {                                                            \
      __hip_atomic_fetch_add(cnt, 1u, __ATOMIC_RELEASE,                        \
                             __HIP_MEMORY_SCOPE_AGENT);                        \
      while (__hip_atomic_load(cnt, __ATOMIC_RELAXED,                          \
                               __HIP_MEMORY_SCOPE_AGENT) < (tgt))              \
        __builtin_amdgcn_s_sleep(8);                                           \
    }                                                                          \
    __syncthreads();                                                           \
  } while (0)

#define COLREDUCE_STORE(dstp)                                                  \
  do {                                                                         \
    if (w < 8) {                                                               \
      f4 sa = {colacc[0], colacc[1], colacc[2], colacc[3]};                    \
      f4 sbv = {colacc[4], colacc[5], colacc[6], colacc[7]};                   \
      *(f4*)&stage[w][j0] = sa;                                                \
      *(f4*)&stage[w][256 + j0] = sbv;                                         \
    }                                                                          \
    __syncthreads();                                                           \
    if (w >= 8) {                                                              \
      f4 sa = *(f4*)&stage[w - 8][j0];                                         \
      f4 sbv = *(f4*)&stage[w - 8][256 + j0];                                  \
      sa[0] += colacc[0]; sa[1] += colacc[1];                                  \
      sa[2] += colacc[2]; sa[3] += colacc[3];                                  \
      sbv[0] += colacc[4]; sbv[1] += colacc[5];                                \
      sbv[2] += colacc[6]; sbv[3] += colacc[7];                                \
      *(f4*)&stage[w - 8][j0] = sa;                                            \
      *(f4*)&stage[w - 8][256 + j0] = sbv;                                     \
    }                                                                          \
    __syncthreads();                                                           \
    if (tid < LDIM) {                                                          \
      float cs = stage[0][tid] + stage[1][tid] + stage[2][tid] +               \
                 stage[3][tid] + stage[4][tid] + stage[5][tid] +               \
                 stage[6][tid] + stage[7][tid];                                \
      st_agent((dstp) + tid, cs);                                              \
    }                                                                          \
  } while (0)

  // One row of the step update; r must be a compile-time constant (rule #20).
#define STEP_ROW(r)                                                            \
  do {                                                                         \
    const int i = wrow + (r);                                                  \
    const int lrow = (w << 3) + (r);                                           \
    const float lmi = lmsgS[i];                                                \
    const h4 mh0 = *(const h4*)&muL[lrow][j0];                                 \
    const h4 mh1 = *(const h4*)&muL[lrow][256 + j0];                           \
    const f4 rh0 = *(const f4*)(rho_p + (size_t)i * LDIM + j0);                \
    const f4 rh1 = *(const f4*)(rho_p + (size_t)i * LDIM + 256 + j0);          \
    float rowc = 0.0f;                                                         \
    _Pragma("unroll") for (int k = 0; k < 4; k++) {                            \
      const float mva = (float)mh0[k];                                         \
      const bool ma = mva > MU_THRESH;                                         \
      const float ga = ma ? (mva - lmi - lmja[k]) : 0.0f;                      \
      const float ua = ahv[r][0][k] * fmaf(rat, ga, 1.0f);                     \
      const float va = fminf(relu_f(fabsf(ua) - rh0[k] * rat), 1.0f);          \
      ahv[r][0][k] = va;                                                       \
      const float ca = ma ? va : 0.0f;                                         \
      rowc += ca;                                                              \
      colacc[k] += ca;                                                         \
      const float mvb = (float)mh1[k];                                         \
      const bool mbk = mvb > MU_THRESH;                                        \
      const float gb = mbk ? (mvb - lmi - lmjb[k]) : 0.0f;                     \
      const float ub = ahv[r][1][k] * fmaf(rat, gb, 1.0f);                     \
      const float vb = fminf(relu_f(fabsf(ub) - rh1[k] * rat), 1.0f);          \
      ahv[r][1][k] = vb;                                                       \
      const float cbv = mbk ? vb : 0.0f;                                       \
      rowc += cbv;                                                             \
      colacc[4 + k] += cbv;                                                    \
    }                                                                          \
    if (!last) {                                                               \
      const float rsum = wave_reduce_sum(rowc);                                \
      if (lane == 0)                                                           \
        st_agent(rowpart + (size_t)(par ^ 1) * RP + (size_t)b * LDIM + i,      \
                 rsum);                                                        \
    }                                                                          \
  } while (0)

  // ---- P_init: A_hat_0 = scores into regs; MU(fp16) into LDS; partials ----
#pragma unroll
  for (int k = 0; k < 8; k++) colacc[k] = 0.0f;
#pragma unroll
  for (int r = 0; r < 8; r++) {
    const int i = wrow + r;
    const size_t base = mb + (size_t)i * LDIM;
    const f4 s0 = *(const f4*)(scores + base + j0);
    const f4 s1 = *(const f4*)(scores + base + 256 + j0);
    const h4 m0 = *(const h4*)(MU + base + j0);
    const h4 m1 = *(const h4*)(MU + base + 256 + j0);
    ahv[r][0] = s0;
    ahv[r][1] = s1;
    const int lrow = (w << 3) + r;
    *(h4*)&muL[lrow][j0] = m0;
    *(h4*)&muL[lrow][256 + j0] = m1;
    float rowc = 0.0f;
#pragma unroll
    for (int k = 0; k < 4; k++) {
      const float c0v = ((float)m0[k] > MU_THRESH) ? s0[k] : 0.0f;
      const float c1v = ((float)m1[k] > MU_THRESH) ? s1[k] : 0.0f;
      rowc += c0v + c1v;
      colacc[k] += c0v;
      colacc[4 + k] += c1v;
    }
    const float rsum = wave_reduce_sum(rowc);
    if (lane == 0) st_agent(rowpart + (size_t)b * LDIM + i, rsum);
    if (r == 3) __builtin_amdgcn_sched_barrier(0);  // cap load hoisting
  }
  COLREDUCE_STORE(colpart + ((size_t)b * 4 + sb) * LDIM);
  ARRIVE_WAIT(4u);

  // ---- 20 steps ----
  for (int sp = 0; sp < NSTEPS; ++sp) {
    const int par = sp & 1;
    // lm phase: identical on all 4 sibling blocks (bit-deterministic).
    if (tid < LDIM) {
      const int i = tid;
      const float rsum = ld_agent(rowpart + (size_t)par * RP + (size_t)b * LDIM + i);
      const float* cb = colpart + (size_t)par * CP + (size_t)b * 4 * LDIM + i;
      const float csum = ld_agent(cb) + ld_agent(cb + LDIM) +
                         ld_agent(cb + 2 * LDIM) + ld_agent(cb + 3 * LDIM);
      const float rd = 0.5f * (rsum + csum) - 1.0f;
      float lm;
      if (sp == 0)
        lm = wv * relu_f(rd);
      else
        lm = lm_reg + belt * lrbp * relu_f(rd);
      lm_reg = lm;
      lmsgS[i] = lm * sign_f(rd);
    }
    __syncthreads();

    const f4 lmja = *(const f4*)&lmsgS[j0];
    const f4 lmjb = *(const f4*)&lmsgS[256 + j0];
    const bool last = (sp == NSTEPS - 1);
    const float rat = at;
#pragma unroll
    for (int k = 0; k < 8; k++) colacc[k] = 0.0f;

    // Two 4-row groups; the sched_barrier stops the scheduler from keeping
    // all 8 rows' MU/rho loads live at once (the round-3 spill trigger).
    STEP_ROW(0); STEP_ROW(1); STEP_ROW(2); STEP_ROW(3);
    __builtin_amdgcn_sched_barrier(0);
    STEP_ROW(4); STEP_ROW(5); STEP_ROW(6); STEP_ROW(7);

    if (!last) {
      COLREDUCE_STORE(colpart + (size_t)(par ^ 1) * CP + ((size_t)b * 4 + sb) * LDIM);
      ARRIVE_WAIT(4u * (unsigned)(sp + 2));
    }
    at *= lra;
    if (sp > 0) lrbp *= lrb;
  }

  // ---- write A_hat_20 out (k_final symmetrizes in place) ----
#pragma unroll
  for (int r = 0; r < 8; r++) {
    const size_t base = mb + (size_t)(wrow + r) * LDIM;
    *(f4*)(Ah + base + j0) = ahv[r][0];
    *(f4*)(Ah + base + 256 + j0) = ahv[r][1];
  }
#undef ARRIVE_WAIT
#undef COLREDUCE_STORE
#undef STEP_ROW
}

// ---------------------------------------------------------------------------
// K_final: in-place A = 0.5*(Ah + Ah^T) .* M over tile pairs (64x64 tiles).
// ---------------------------------------------------------------------------
__global__ __launch_bounds__(NTHREADS) void k_final(float* __restrict__ Ah,
                                                    const float* __restrict__ M) {
  __shared__ float At[64][65];
  __shared__ float Bt[64][65];
  const int b = blockIdx.x / 36;
  int rem = blockIdx.x % 36;
  int ti = 0;
  while (rem >= 8 - ti) {
    rem -= 8 - ti;
    ti++;
  }
  const int tj = ti + rem;
  const int tid = threadIdx.x;
  const int c = tid & 63;
  const int r0 = tid >> 6;
  const size_t mb = (size_t)b * LDIM * LDIM;

#pragma unroll
  for (int k = 0; k < 16; k++) {
    const int r = 4 * k + r0;
    At[r][c] = Ah[mb + (size_t)(ti * 64 + r) * LDIM + tj * 64 + c];
    Bt[r][c] = Ah[mb + (size_t)(tj * 64 + r) * LDIM + ti * 64 + c];
  }
  __syncthreads();
#pragma unroll
  for (int k = 0; k < 16; k++) {
    const int r = 4 * k + r0;
    const size_t idx_ij = mb + (size_t)(ti * 64 + r) * LDIM + tj * 64 + c;
    const float mij = M[idx_ij];
    Ah[idx_ij] = 0.5f * (At[r][c] + Bt[c][r]) * mij;
    if (ti != tj) {
      const size_t idx_ji = mb + (size_t)(tj * 64 + r) * LDIM + ti * 64 + c;
      const float mji = M[idx_ji];
      Ah[idx_ji] = 0.5f * (Bt[r][c] + At[c][r]) * mji;
    }
  }
}

// ---------------------------------------------------------------------------
extern "C" void kernel_launch(void* const* d_in, const int* in_sizes, int n_in,
                              void* d_out, int out_size, void* d_ws,
                              size_t ws_size, hipStream_t stream) {
  const float* scores = (const float*)d_in[0];
  const float* M = (const float*)d_in[1];
  const float* s_p = (const float*)d_in[2];
  const float* w_p = (const float*)d_in[3];
  const float* rho = (const float*)d_in[4];
  const float* alpha_p = (const float*)d_in[5];
  const float* belt_p = (const float*)d_in[6];
  const float* lra_p = (const float*)d_in[7];
  const float* lrb_p = (const float*)d_in[8];
  float* Ah = (float*)d_out;

  char* ws = (char*)d_ws;
  size_t off = 0;
  auto walloc = [&](size_t bytes) -> void* {
    void* p = (void*)(ws + off);
    off += (bytes + 255) & ~(size_t)255;
    return p;
  };
  const size_t NEL = (size_t)BATCH * LDIM * LDIM;
  _Float16* MU = (_Float16*)walloc(NEL * 2);                        // 32 MB
  float* rowpart = (float*)walloc((size_t)2 * BATCH * LDIM * 4);    // 256 KB
  float* colpart = (float*)walloc((size_t)2 * BATCH * 4 * LDIM * 4);// 1 MB
  unsigned int* cnt = (unsigned int*)walloc(BATCH * CNT_STRIDE * 4);// 4 KB
  (void)in_sizes;
  (void)n_in;
  (void)out_size;
  (void)ws_size;

  k_build<<<dim3(BATCH * 36), dim3(NTHREADS), 0, stream>>>(scores, M, s_p, MU,
                                                           cnt);

  void* args[] = {(void*)&scores, (void*)&MU,      (void*)&rho,
                  (void*)&w_p,    (void*)&alpha_p, (void*)&belt_p,
                  (void*)&lra_p,  (void*)&lrb_p,   (void*)&rowpart,
                  (void*)&colpart, (void*)&cnt,    (void*)&Ah};
  hipError_t cerr = hipLaunchCooperativeKernel(
      (const void*)k_persist, dim3(BATCH * 4), dim3(PTHREADS), args, 0, stream);
  if (cerr != hipSuccess) {
    // Fallback: plain launch. 256 blocks at 1 block/CU on a 256-CU chip are
    // trivially co-resident; the per-batch counter sync is unchanged.
    k_persist<<<dim3(BATCH * 4), dim3(PTHREADS), 0, stream>>>(
        scores, MU, rho, w_p, alpha_p, belt_p, lra_p, lrb_p, rowpart, colpart,
        cnt, Ah);
  }

  k_final<<<dim3(BATCH * 36), dim3(NTHREADS), 0, stream>>>(Ah, M);
}

// Round 5
// 795.141 us; speedup vs baseline: 1.2840x; 1.2840x over previous
//
#include <hip/hip_runtime.h>
#include <cstdint>
#include <cstddef>

// Problem constants (match reference: B=64, L=512, STEPS=20)
#define LDIM 512
#define BATCH 64
#define NSTEPS 20
#define NTHREADS 256
#define PTHREADS 1024
#define CNT_STRIDE 16  // 64 B per counter: no atomic line sharing across batches

using f4 = __attribute__((ext_vector_type(4))) float;
using h4 = __attribute__((ext_vector_type(4))) _Float16;

#define MU_MASKED (-1024.0f)   // exact in fp16; sentinel for M==0
#define MU_THRESH (-512.0f)

__device__ __forceinline__ float relu_f(float x) { return fmaxf(x, 0.0f); }
__device__ __forceinline__ float sign_f(float x) {
  return (x > 0.0f) ? 1.0f : ((x < 0.0f) ? -1.0f : 0.0f);
}
__device__ __forceinline__ float wave_reduce_sum(float v) {
  v += __shfl_xor(v, 32);
  v += __shfl_xor(v, 16);
  v += __shfl_xor(v, 8);
  v += __shfl_xor(v, 4);
  v += __shfl_xor(v, 2);
  v += __shfl_xor(v, 1);
  return v;
}
// Agent-scope RELAXED accesses: compile to sc1 (L1/L2-bypassing) ops serviced
// at the coherence point. Never acquire/threadfence here: agent-acquire emits
// buffer_inv (full per-XCD L2 invalidate) — round-1 spent 97% of time there.
__device__ __forceinline__ void st_agent(float* p, float v) {
  __hip_atomic_store(p, v, __ATOMIC_RELAXED, __HIP_MEMORY_SCOPE_AGENT);
}
__device__ __forceinline__ float ld_agent(const float* p) {
  return __hip_atomic_load(p, __ATOMIC_RELAXED, __HIP_MEMORY_SCOPE_AGENT);
}

// ---------------------------------------------------------------------------
// k_build: MU[b][i][j] = M_ij ? fp16(0.5*(sc_ij + sc_ji) - s) : -1024, via
// 64x64 tile pairs (coalesced transpose through LDS). Also zeroes the
// per-batch sync counters (flushed by the end-of-kernel release).
// Grid: BATCH * 36 tile pairs; 256 threads.
// ---------------------------------------------------------------------------
__global__ __launch_bounds__(NTHREADS) void k_build(
    const float* __restrict__ scores, const float* __restrict__ M,
    const float* __restrict__ s_ptr, _Float16* __restrict__ MU,
    unsigned int* __restrict__ counter) {
  __shared__ float Sa[64][65];
  __shared__ float Sb[64][65];
  if (blockIdx.x < BATCH && threadIdx.x == 0) counter[blockIdx.x * CNT_STRIDE] = 0u;
  const int b = blockIdx.x / 36;
  int rem = blockIdx.x % 36;
  int ti = 0;
  while (rem >= 8 - ti) {
    rem -= 8 - ti;
    ti++;
  }
  const int tj = ti + rem;
  const int tid = threadIdx.x;
  const int c = tid & 63;
  const int r0 = tid >> 6;
  const float sval = s_ptr[0];
  const size_t mb = (size_t)b * LDIM * LDIM;
#pragma unroll
  for (int k = 0; k < 16; k++) {
    const int r = 4 * k + r0;
    Sa[r][c] = scores[mb + (size_t)(ti * 64 + r) * LDIM + tj * 64 + c];
    Sb[r][c] = scores[mb + (size_t)(tj * 64 + r) * LDIM + ti * 64 + c];
  }
  __syncthreads();
#pragma unroll
  for (int k = 0; k < 16; k++) {
    const int r = 4 * k + r0;
    const size_t idx_ij = mb + (size_t)(ti * 64 + r) * LDIM + tj * 64 + c;
    const float mij = M[idx_ij];
    const float us = 0.5f * (Sa[r][c] + Sb[c][r]) - sval;
    MU[idx_ij] = (_Float16)((mij != 0.0f) ? us : MU_MASKED);
    if (ti != tj) {
      const size_t idx_ji = mb + (size_t)(tj * 64 + r) * LDIM + ti * 64 + c;
      const float mji = M[idx_ji];
      const float usj = 0.5f * (Sb[r][c] + Sa[c][r]) - sval;
      MU[idx_ji] = (_Float16)((mji != 0.0f) ? usj : MU_MASKED);
    }
  }
}

// ---------------------------------------------------------------------------
// k_persist: all 20 steps with A_hat resident on-chip; MU (fp16) STREAMED
// from global each step (L2/L3-serviced; 32 MB/step chip-wide — half of
// round-2's fp32 stream, which was the measured per-step cost).
// Grid 256 blocks x 1024 threads, 1 block/CU. Block (b = blockIdx&63,
// sb = blockIdx>>6) owns rows [sb*128, sb*128+128) of batch b.
// Per wave (16 waves): 8 rows; rows 0..3 in VGPRs (ahv[4][2] = 32 regs, the
// empirically spill-free state size at the 64-VGPR budget this toolchain
// pins for 1024-thread blocks — rounds 3/4 proved 64-reg state spills),
// rows 4..7 in LDS ahL fp32 (128 KB).
// Cross-block exchange per step: 2.5 KB of partials via sc1 relaxed atomics +
// a monotonic per-batch arrival counter. NO fences, NO acquire.
// ---------------------------------------------------------------------------
__global__ __launch_bounds__(PTHREADS, 4) void k_persist(
    const float* __restrict__ scores, const _Float16* __restrict__ MU,
    const float* __restrict__ rho_p, const float* __restrict__ w_ptr,
    const float* __restrict__ alpha_ptr, const float* __restrict__ belt_ptr,
    const float* __restrict__ lra_ptr, const float* __restrict__ lrb_ptr,
    float* __restrict__ rowpart, float* __restrict__ colpart,
    unsigned int* __restrict__ counter, float* __restrict__ Ah) {
  __shared__ float ahL[64][LDIM];    // 128 KB: LDS-resident half of A_hat slab
  __shared__ float stage[8][LDIM];   // 16 KB: cross-wave col-sum staging
  __shared__ float lmsgS[LDIM];      // 2 KB   (total 146 KB <= 160 KB)

  const int tid = threadIdx.x;
  const int lane = tid & 63;
  const int w = tid >> 6;
  const int b = blockIdx.x & (BATCH - 1);
  const int sb = blockIdx.x >> 6;
  const int wrow = sb * 128 + w * 8;
  const int j0 = lane << 2;
  const size_t mb = (size_t)b * LDIM * LDIM;

  const float wv = w_ptr[0];
  const float belt = belt_ptr[0];
  const float lra = lra_ptr[0];
  const float lrb = lrb_ptr[0];
  float at = alpha_ptr[0];  // a_t = alpha * lra^sp, updated iteratively
  float lrbp = 1.0f;        // lrb^(sp-1) for sp>=1
  float lm_reg = 0.0f;      // Lm[tid] (valid for tid < LDIM)

  const size_t RP = (size_t)BATCH * LDIM;      // rowpart parity stride
  const size_t CP = (size_t)BATCH * 4 * LDIM;  // colpart parity stride
  unsigned int* const cnt = counter + b * CNT_STRIDE;

  f4 ahv[4][2];
  float colacc[8];

  // __syncthreads() drains vmcnt per wave, so all waves' sc1 partial stores
  // are at the coherence point before tid0's counter add. Spin load is
  // RELAXED (sc1 loads always read fresh; no cache maintenance).
#define ARRIVE_WAIT(tgt)                                                       \
  do {                                                                         \
    __syncthreads();                                                           \
    if (tid == 0) {                                                            \
      __hip_atomic_fetch_add(cnt, 1u, __ATOMIC_RELEASE,                        \
                             __HIP_MEMORY_SCOPE_AGENT);                        \
      while (__hip_atomic_load(cnt, __ATOMIC_RELAXED,                          \
                               __HIP_MEMORY_SCOPE_AGENT) < (tgt))              \
        __builtin_amdgcn_s_sleep(8);                                           \
    }                                                                          \
    __syncthreads();                                                           \
  } while (0)

#define COLREDUCE_STORE(dstp)                                                  \
  do {                                                                         \
    if (w < 8) {                                                               \
      f4 sa = {colacc[0], colacc[1], colacc[2], colacc[3]};                    \
      f4 sbv = {colacc[4], colacc[5], colacc[6], colacc[7]};                   \
      *(f4*)&stage[w][j0] = sa;                                                \
      *(f4*)&stage[w][256 + j0] = sbv;                                         \
    }                                                                          \
    __syncthreads();                                                           \
    if (w >= 8) {                                                              \
      f4 sa = *(f4*)&stage[w - 8][j0];                                         \
      f4 sbv = *(f4*)&stage[w - 8][256 + j0];                                  \
      sa[0] += colacc[0]; sa[1] += colacc[1];                                  \
      sa[2] += colacc[2]; sa[3] += colacc[3];                                  \
      sbv[0] += colacc[4]; sbv[1] += colacc[5];                                \
      sbv[2] += colacc[6]; sbv[3] += colacc[7];                                \
      *(f4*)&stage[w - 8][j0] = sa;                                            \
      *(f4*)&stage[w - 8][256 + j0] = sbv;                                     \
    }                                                                          \
    __syncthreads();                                                           \
    if (tid < LDIM) {                                                          \
      float cs = stage[0][tid] + stage[1][tid] + stage[2][tid] +               \
                 stage[3][tid] + stage[4][tid] + stage[5][tid] +               \
                 stage[6][tid] + stage[7][tid];                                \
      st_agent((dstp) + tid, cs);                                              \
    }                                                                          \
  } while (0)

  // ---- P_init: A_hat_0 = scores into regs/LDS; partials of M .* A_hat_0 ----
#pragma unroll
  for (int k = 0; k < 8; k++) colacc[k] = 0.0f;
#pragma unroll
  for (int r = 0; r < 8; r++) {
    const int i = wrow + r;
    const size_t base = mb + (size_t)i * LDIM;
    const f4 s0 = *(const f4*)(scores + base + j0);
    const f4 s1 = *(const f4*)(scores + base + 256 + j0);
    const h4 m0 = *(const h4*)(MU + base + j0);
    const h4 m1 = *(const h4*)(MU + base + 256 + j0);
    if (r < 4) {
      ahv[r][0] = s0;
      ahv[r][1] = s1;
    } else {
      *(f4*)&ahL[(w << 2) + (r - 4)][j0] = s0;
      *(f4*)&ahL[(w << 2) + (r - 4)][256 + j0] = s1;
    }
    float rowc = 0.0f;
#pragma unroll
    for (int k = 0; k < 4; k++) {
      const float c0v = ((float)m0[k] > MU_THRESH) ? s0[k] : 0.0f;
      const float c1v = ((float)m1[k] > MU_THRESH) ? s1[k] : 0.0f;
      rowc += c0v + c1v;
      colacc[k] += c0v;
      colacc[4 + k] += c1v;
    }
    const float rsum = wave_reduce_sum(rowc);
    if (lane == 0) st_agent(rowpart + (size_t)b * LDIM + i, rsum);
  }
  COLREDUCE_STORE(colpart + ((size_t)b * 4 + sb) * LDIM);
  ARRIVE_WAIT(4u);

  // ---- 20 steps ----
  for (int sp = 0; sp < NSTEPS; ++sp) {
    const int par = sp & 1;
    // lm phase: identical on all 4 sibling blocks (bit-deterministic).
    if (tid < LDIM) {
      const int i = tid;
      const float rsum = ld_agent(rowpart + (size_t)par * RP + (size_t)b * LDIM + i);
      const float* cb = colpart + (size_t)par * CP + (size_t)b * 4 * LDIM + i;
      const float csum = ld_agent(cb) + ld_agent(cb + LDIM) +
                         ld_agent(cb + 2 * LDIM) + ld_agent(cb + 3 * LDIM);
      const float rd = 0.5f * (rsum + csum) - 1.0f;
      float lm;
      if (sp == 0)
        lm = wv * relu_f(rd);
      else
        lm = lm_reg + belt * lrbp * relu_f(rd);
      lm_reg = lm;
      lmsgS[i] = lm * sign_f(rd);
    }
    __syncthreads();

    const f4 lmja = *(const f4*)&lmsgS[j0];
    const f4 lmjb = *(const f4*)&lmsgS[256 + j0];
    const bool last = (sp == NSTEPS - 1);
    const float rat = at;
#pragma unroll
    for (int k = 0; k < 8; k++) colacc[k] = 0.0f;

    // VGPR-resident rows
#pragma unroll
    for (int r = 0; r < 4; r++) {
      const int i = wrow + r;
      const size_t base = mb + (size_t)i * LDIM;
      const float lmi = lmsgS[i];
      const h4 mh0 = *(const h4*)(MU + base + j0);
      const h4 mh1 = *(const h4*)(MU + base + 256 + j0);
      const f4 rh0 = *(const f4*)(rho_p + (size_t)i * LDIM + j0);
      const f4 rh1 = *(const f4*)(rho_p + (size_t)i * LDIM + 256 + j0);
      float rowc = 0.0f;
#pragma unroll
      for (int k = 0; k < 4; k++) {
        const float mva = (float)mh0[k];
        const bool ma = mva > MU_THRESH;
        const float ga = ma ? (mva - lmi - lmja[k]) : 0.0f;
        const float ua = ahv[r][0][k] * fmaf(rat, ga, 1.0f);
        const float va = fminf(relu_f(fabsf(ua) - rh0[k] * rat), 1.0f);
        ahv[r][0][k] = va;
        const float ca = ma ? va : 0.0f;
        rowc += ca;
        colacc[k] += ca;
        const float mvb = (float)mh1[k];
        const bool mbk = mvb > MU_THRESH;
        const float gb = mbk ? (mvb - lmi - lmjb[k]) : 0.0f;
        const float ub = ahv[r][1][k] * fmaf(rat, gb, 1.0f);
        const float vb = fminf(relu_f(fabsf(ub) - rh1[k] * rat), 1.0f);
        ahv[r][1][k] = vb;
        const float cbv = mbk ? vb : 0.0f;
        rowc += cbv;
        colacc[4 + k] += cbv;
      }
      if (!last) {
        const float rsum = wave_reduce_sum(rowc);
        if (lane == 0)
          st_agent(rowpart + (size_t)(par ^ 1) * RP + (size_t)b * LDIM + i, rsum);
      }
    }
    // LDS-resident rows
#pragma unroll 2
    for (int r = 4; r < 8; r++) {
      const int i = wrow + r;
      const size_t base = mb + (size_t)i * LDIM;
      const int lr = (w << 2) + (r - 4);
      const float lmi = lmsgS[i];
      const h4 mh0 = *(const h4*)(MU + base + j0);
      const h4 mh1 = *(const h4*)(MU + base + 256 + j0);
      const f4 rh0 = *(const f4*)(rho_p + (size_t)i * LDIM + j0);
      const f4 rh1 = *(const f4*)(rho_p + (size_t)i * LDIM + 256 + j0);
      f4 a0 = *(const f4*)&ahL[lr][j0];
      f4 a1 = *(const f4*)&ahL[lr][256 + j0];
      float rowc = 0.0f;
#pragma unroll
      for (int k = 0; k < 4; k++) {
        const float mva = (float)mh0[k];
        const bool ma = mva > MU_THRESH;
        const float ga = ma ? (mva - lmi - lmja[k]) : 0.0f;
        const float ua = a0[k] * fmaf(rat, ga, 1.0f);
        const float va = fminf(relu_f(fabsf(ua) - rh0[k] * rat), 1.0f);
        a0[k] = va;
        const float ca = ma ? va : 0.0f;
        rowc += ca;
        colacc[k] += ca;
        const float mvb = (float)mh1[k];
        const bool mbk = mvb > MU_THRESH;
        const float gb = mbk ? (mvb - lmi - lmjb[k]) : 0.0f;
        const float ub = a1[k] * fmaf(rat, gb, 1.0f);
        const float vb = fminf(relu_f(fabsf(ub) - rh1[k] * rat), 1.0f);
        a1[k] = vb;
        const float cbv = mbk ? vb : 0.0f;
        rowc += cbv;
        colacc[4 + k] += cbv;
      }
      *(f4*)&ahL[lr][j0] = a0;
      *(f4*)&ahL[lr][256 + j0] = a1;
      if (!last) {
        const float rsum = wave_reduce_sum(rowc);
        if (lane == 0)
          st_agent(rowpart + (size_t)(par ^ 1) * RP + (size_t)b * LDIM + i, rsum);
      }
    }
    if (!last) {
      COLREDUCE_STORE(colpart + (size_t)(par ^ 1) * CP + ((size_t)b * 4 + sb) * LDIM);
      ARRIVE_WAIT(4u * (unsigned)(sp + 2));
    }
    at *= lra;
    if (sp > 0) lrbp *= lrb;
  }

  // ---- write A_hat_20 out (k_final symmetrizes in place) ----
#pragma unroll
  for (int r = 0; r < 4; r++) {
    const size_t base = mb + (size_t)(wrow + r) * LDIM;
    *(f4*)(Ah + base + j0) = ahv[r][0];
    *(f4*)(Ah + base + 256 + j0) = ahv[r][1];
  }
#pragma unroll
  for (int r = 4; r < 8; r++) {
    const size_t base = mb + (size_t)(wrow + r) * LDIM;
    const int lr = (w << 2) + (r - 4);
    *(f4*)(Ah + base + j0) = *(const f4*)&ahL[lr][j0];
    *(f4*)(Ah + base + 256 + j0) = *(const f4*)&ahL[lr][256 + j0];
  }
#undef ARRIVE_WAIT
#undef COLREDUCE_STORE
}

// ---------------------------------------------------------------------------
// K_final: in-place A = 0.5*(Ah + Ah^T) .* M over tile pairs (64x64 tiles).
// ---------------------------------------------------------------------------
__global__ __launch_bounds__(NTHREADS) void k_final(float* __restrict__ Ah,
                                                    const float* __restrict__ M) {
  __shared__ float At[64][65];
  __shared__ float Bt[64][65];
  const int b = blockIdx.x / 36;
  int rem = blockIdx.x % 36;
  int ti = 0;
  while (rem >= 8 - ti) {
    rem -= 8 - ti;
    ti++;
  }
  const int tj = ti + rem;
  const int tid = threadIdx.x;
  const int c = tid & 63;
  const int r0 = tid >> 6;
  const size_t mb = (size_t)b * LDIM * LDIM;

#pragma unroll
  for (int k = 0; k < 16; k++) {
    const int r = 4 * k + r0;
    At[r][c] = Ah[mb + (size_t)(ti * 64 + r) * LDIM + tj * 64 + c];
    Bt[r][c] = Ah[mb + (size_t)(tj * 64 + r) * LDIM + ti * 64 + c];
  }
  __syncthreads();
#pragma unroll
  for (int k = 0; k < 16; k++) {
    const int r = 4 * k + r0;
    const size_t idx_ij = mb + (size_t)(ti * 64 + r) * LDIM + tj * 64 + c;
    const float mij = M[idx_ij];
    Ah[idx_ij] = 0.5f * (At[r][c] + Bt[c][r]) * mij;
    if (ti != tj) {
      const size_t idx_ji = mb + (size_t)(tj * 64 + r) * LDIM + ti * 64 + c;
      const float mji = M[idx_ji];
      Ah[idx_ji] = 0.5f * (Bt[r][c] + At[c][r]) * mji;
    }
  }
}

// ---------------------------------------------------------------------------
extern "C" void kernel_launch(void* const* d_in, const int* in_sizes, int n_in,
                              void* d_out, int out_size, void* d_ws,
                              size_t ws_size, hipStream_t stream) {
  const float* scores = (const float*)d_in[0];
  const float* M = (const float*)d_in[1];
  const float* s_p = (const float*)d_in[2];
  const float* w_p = (const float*)d_in[3];
  const float* rho = (const float*)d_in[4];
  const float* alpha_p = (const float*)d_in[5];
  const float* belt_p = (const float*)d_in[6];
  const float* lra_p = (const float*)d_in[7];
  const float* lrb_p = (const float*)d_in[8];
  float* Ah = (float*)d_out;

  char* ws = (char*)d_ws;
  size_t off = 0;
  auto walloc = [&](size_t bytes) -> void* {
    void* p = (void*)(ws + off);
    off += (bytes + 255) & ~(size_t)255;
    return p;
  };
  const size_t NEL = (size_t)BATCH * LDIM * LDIM;
  _Float16* MU = (_Float16*)walloc(NEL * 2);                        // 32 MB
  float* rowpart = (float*)walloc((size_t)2 * BATCH * LDIM * 4);    // 256 KB
  float* colpart = (float*)walloc((size_t)2 * BATCH * 4 * LDIM * 4);// 1 MB
  unsigned int* cnt = (unsigned int*)walloc(BATCH * CNT_STRIDE * 4);// 4 KB
  (void)in_sizes;
  (void)n_in;
  (void)out_size;
  (void)ws_size;

  k_build<<<dim3(BATCH * 36), dim3(NTHREADS), 0, stream>>>(scores, M, s_p, MU,
                                                           cnt);

  void* args[] = {(void*)&scores, (void*)&MU,      (void*)&rho,
                  (void*)&w_p,    (void*)&alpha_p, (void*)&belt_p,
                  (void*)&lra_p,  (void*)&lrb_p,   (void*)&rowpart,
                  (void*)&colpart, (void*)&cnt,    (void*)&Ah};
  hipError_t cerr = hipLaunchCooperativeKernel(
      (const void*)k_persist, dim3(BATCH * 4), dim3(PTHREADS), args, 0, stream);
  if (cerr != hipSuccess) {
    // Fallback: plain launch. 256 blocks at 1 block/CU on a 256-CU chip are
    // trivially co-resident; the per-batch counter sync is unchanged.
    k_persist<<<dim3(BATCH * 4), dim3(PTHREADS), 0, stream>>>(
        scores, MU, rho, w_p, alpha_p, belt_p, lra_p, lrb_p, rowpart, colpart,
        cnt, Ah);
  }

  k_final<<<dim3(BATCH * 36), dim3(NTHREADS), 0, stream>>>(Ah, M);
}